// Round 12
// baseline (439.968 us; speedup 1.0000x reference)
//
#include <hip/hip_runtime.h>
#include <hip/hip_bf16.h>

#define HID 128
#define IN_DIM 16
#define LDST 136   // LDS row stride in bf16 elems (272 B)
#define NBSH 6     // bucket = dst >> 6  (64 dsts/bucket)
#define BPAD 16    // bucket counter padding (ints) -> one 64B line per counter
#define SRCM 0x3ffffffu
#define CH 8192    // edges per chunk (preph hist)
#define CHB 2048   // edges per chunk (bin_k) - r11: 4x more blocks, latency hiding
#define NBMAX 1024
#define NDPW 4     // sequential dsts per wave in msg_k

typedef unsigned short u16;
typedef __attribute__((ext_vector_type(8))) short short8;
typedef __attribute__((ext_vector_type(4))) float f32x4;

__device__ __forceinline__ u16 f2b(float f) {  // RNE
    unsigned u = __float_as_uint(f);
    return (u16)((u + 0x7FFF + ((u >> 16) & 1)) >> 16);
}

// ---------------- graph prep ----------------

__global__ __launch_bounds__(1024) void bscan_k(const int* __restrict__ bktcnt, int* __restrict__ bktbase,
                                                int* __restrict__ bcnt, int* __restrict__ row_ptr,
                                                int nb, int n, int E) {
    __shared__ int sbuf[1024];
    int t = threadIdx.x;
    int v = (t < nb) ? bktcnt[t] : 0;
    sbuf[t] = v;
    __syncthreads();
    for (int off = 1; off < 1024; off <<= 1) {
        int a = (t >= off) ? sbuf[t - off] : 0;
        __syncthreads();
        sbuf[t] += a;
        __syncthreads();
    }
    if (t < nb) {
        int excl = sbuf[t] - v;
        bktbase[t] = excl;
        bcnt[t * BPAD] = excl;
    }
    if (t == 0) { bktbase[nb] = E; row_ptr[n] = E; }
}

// r11: CHB=2048 chunks -> 782 blocks, ~25.6KB LDS each (~3 resident/CU) so the
// serial hist->scan->scatter chain of one block hides under its neighbors'.
__global__ __launch_bounds__(256) void bin_k(const int* __restrict__ src, const int* __restrict__ dst,
                                             int* __restrict__ bcnt, unsigned* __restrict__ ebuf,
                                             int E, int nb) {
    __shared__ unsigned stage[CHB];
    __shared__ u16 sbk[CHB];
    __shared__ int hist[NBMAX];
    __shared__ int lofs[NBMAX];
    __shared__ int sbase[NBMAX];
    __shared__ int scan256[256];
    int tid = threadIdx.x;
    int base = blockIdx.x * CHB;
    int cnt = E - base; if (cnt > CHB) cnt = CHB;

    for (int i = tid; i < nb; i += 256) hist[i] = 0;
    __syncthreads();
    for (int j = tid; j < cnt; j += 256) {
        int d = dst[base + j];
        atomicAdd(&hist[d >> NBSH], 1);
    }
    __syncthreads();
    int psum[4];
    int ts = 0;
#pragma unroll
    for (int q = 0; q < 4; q++) {
        int idx = tid * 4 + q;
        int hv = (idx < nb) ? hist[idx] : 0;
        psum[q] = ts;
        ts += hv;
    }
    scan256[tid] = ts;
    __syncthreads();
    for (int off = 1; off < 256; off <<= 1) {
        int a = (tid >= off) ? scan256[tid - off] : 0;
        __syncthreads();
        scan256[tid] += a;
        __syncthreads();
    }
    int tbase = (tid > 0) ? scan256[tid - 1] : 0;
#pragma unroll
    for (int q = 0; q < 4; q++) {
        int idx = tid * 4 + q;
        if (idx < nb) lofs[idx] = tbase + psum[q];
    }
    __syncthreads();
    for (int i = tid; i < nb; i += 256) {
        int c = hist[i];
        if (c > 0) {
            int g = atomicAdd(&bcnt[i * BPAD], c);
            sbase[i] = g - lofs[i];
        }
    }
    __syncthreads();
    for (int j = tid; j < cnt; j += 256) {
        int e = base + j;
        int d = dst[e];
        int b = d >> NBSH;
        int r = atomicAdd(&lofs[b], 1);
        stage[r] = (unsigned)src[e] | ((unsigned)(d & 63) << 26);
        sbk[r] = (u16)b;
    }
    __syncthreads();
    for (int s = tid; s < cnt; s += 256) {
        int b = sbk[s];
        ebuf[sbase[b] + s] = stage[s];
    }
}

// ---------------- fused weight prep + histogram + zeroing ----------------
// blocks [0,nj): weight jobs (block 0 also zeros gsums);
// blocks [nj,nj+cg): dst histogram chunks (CH=8192 each).
// ks==5: fp32 [16,128] -> K=32 zero-padded MFMA B-fragment [half][ni][lane][8]
// ks==8: fp32 [128,128] -> MFMA B-fragment [half][kk][ni][lane][8]
//        elem j of lane (quad,ln15) = W[kk*32+quad*8+j][half*64+ni*16+ln15].

struct WJobs {
    const float* src[16];
    int dstoff[16];
    int ks[16];
};

__global__ __launch_bounds__(256) void preph_k(WJobs j, u16* __restrict__ Wt,
                                               const int* __restrict__ dst, int* __restrict__ bktcnt,
                                               float* __restrict__ gsums, int gz,
                                               int E, int nb, int nj) {
    __shared__ int hist[NBMAX];
    int tid = threadIdx.x;
    if ((int)blockIdx.x >= nj) {
        int base = (blockIdx.x - nj) * CH;
        int cnt = E - base; if (cnt > CH) cnt = CH;
        for (int i = tid; i < nb; i += 256) hist[i] = 0;
        __syncthreads();
        for (int jx = tid; jx < cnt; jx += 256) atomicAdd(&hist[dst[base + jx] >> NBSH], 1);
        __syncthreads();
        for (int i = tid; i < nb; i += 256) {
            int c = hist[i];
            if (c > 0) atomicAdd(&bktcnt[i], c);
        }
        return;
    }
    int m = blockIdx.x;
    if (m == 0) {
        for (int i = tid; i < gz; i += 256) gsums[i] = 0.f;
    }
    const float* s = j.src[m];
    u16* d = Wt + j.dstoff[m];
    if (j.ks[m] == 5) {  // W0: 16x128, K padded to 32 with zeros
        for (int idx = tid; idx < 4096; idx += 256) {
            int jj = idx & 7;
            int lane = (idx >> 3) & 63;
            int ni = (idx >> 9) & 3;
            int half = (idx >> 11) & 1;
            int k = ((lane >> 4) << 3) + jj;
            int col = half * 64 + ni * 16 + (lane & 15);
            d[idx] = (k < IN_DIM) ? f2b(s[k * HID + col]) : (u16)0;
        }
    } else {  // ks==8: 128x128
        for (int idx = tid; idx < 16384; idx += 256) {
            int jj = idx & 7;
            int lane = (idx >> 3) & 63;
            int ni = (idx >> 9) & 3;
            int kk = (idx >> 11) & 3;
            int half = idx >> 13;
            int k = kk * 32 + (lane >> 4) * 8 + jj;
            int col = half * 64 + ni * 16 + (lane & 15);
            d[idx] = f2b(s[k * HID + col]);
        }
    }
}

// ---------------- message aggregation (r4-proven, unchanged) ----------------

__device__ __forceinline__ void unpack_add(uint4 v, float* a) {
    a[0] += __uint_as_float(v.x << 16);
    a[1] += __uint_as_float(v.x & 0xffff0000u);
    a[2] += __uint_as_float(v.y << 16);
    a[3] += __uint_as_float(v.y & 0xffff0000u);
    a[4] += __uint_as_float(v.z << 16);
    a[5] += __uint_as_float(v.z & 0xffff0000u);
    a[6] += __uint_as_float(v.w << 16);
    a[7] += __uint_as_float(v.w & 0xffff0000u);
}

__global__ __launch_bounds__(256) void msg_k(const u16* __restrict__ hb, const int* __restrict__ row_ptr,
                                             const int* __restrict__ srcs, u16* __restrict__ msgb, int n,
                                             const float* __restrict__ gsumIn, const float* __restrict__ Wg,
                                             const float* __restrict__ b0, float* __restrict__ grW) {
    if (blockIdx.x == gridDim.x - 1) {
        __shared__ float sred[2];
        __shared__ float sgr[HID];
        int t = threadIdx.x;
        if (t < HID) {
            float g = gsumIn[t];
            float s = g * g;
#pragma unroll
            for (int off = 1; off < 64; off <<= 1) s += __shfl_xor(s, off);
            if ((t & 63) == 0) sred[t >> 6] = s;
        }
        __syncthreads();
        if (t < HID) {
            float inv = 1.f / (sqrtf(sred[0] + sred[1]) + 1e-8f);
            sgr[t] = gsumIn[t] * inv;
        }
        __syncthreads();
        if (t < HID) {
            float a = b0[t];
#pragma unroll 4
            for (int k = 0; k < HID; k++) a += sgr[k] * Wg[k * HID + t];
            grW[t] = a;
        }
        return;
    }
    int wave = threadIdx.x >> 6, lane = threadIdx.x & 63;
    int g = lane >> 4;
    int l16 = lane & 15;
    int d0 = (blockIdx.x * 4 + wave) * NDPW;
    if (d0 >= n) return;
    int eNext = row_ptr[d0];
#pragma unroll 1
    for (int k = 0; k < NDPW; k++) {
        int d = d0 + k;
        if (d >= n) break;
        int e = eNext;
        int e1 = row_ptr[d + 1];
        eNext = e1;
        float a[8] = {0.f, 0.f, 0.f, 0.f, 0.f, 0.f, 0.f, 0.f};
        int s0 = 0, s1 = 0, s2 = 0, s3 = 0;
        if (e + 15 < e1) {
            s0 = srcs[e + g]; s1 = srcs[e + 4 + g];
            s2 = srcs[e + 8 + g]; s3 = srcs[e + 12 + g];
        }
        while (e + 15 < e1) {
            int t0 = s0, t1 = s1, t2 = s2, t3 = s3;
            int en = e + 16;
            if (en + 15 < e1) {
                s0 = srcs[en + g]; s1 = srcs[en + 4 + g];
                s2 = srcs[en + 8 + g]; s3 = srcs[en + 12 + g];
            }
            uint4 v0 = *(const uint4*)(hb + (size_t)t0 * HID + l16 * 8);
            uint4 v1 = *(const uint4*)(hb + (size_t)t1 * HID + l16 * 8);
            uint4 v2 = *(const uint4*)(hb + (size_t)t2 * HID + l16 * 8);
            uint4 v3 = *(const uint4*)(hb + (size_t)t3 * HID + l16 * 8);
            unpack_add(v0, a);
            unpack_add(v1, a);
            unpack_add(v2, a);
            unpack_add(v3, a);
            e = en;
        }
        if (e + 7 < e1) {
            int t0 = srcs[e + g], t1 = srcs[e + 4 + g];
            uint4 v0 = *(const uint4*)(hb + (size_t)t0 * HID + l16 * 8);
            uint4 v1 = *(const uint4*)(hb + (size_t)t1 * HID + l16 * 8);
            unpack_add(v0, a);
            unpack_add(v1, a);
            e += 8;
        }
        if (e + 3 < e1) {
            int s = srcs[e + g];
            uint4 v = *(const uint4*)(hb + (size_t)s * HID + l16 * 8);
            unpack_add(v, a);
            e += 4;
        }
        if (e + g < e1) {
            int s = srcs[e + g];
            uint4 v = *(const uint4*)(hb + (size_t)s * HID + l16 * 8);
            unpack_add(v, a);
        }
#pragma unroll
        for (int i = 0; i < 8; i++) {
            a[i] += __shfl_xor(a[i], 16);
            a[i] += __shfl_xor(a[i], 32);
        }
        if (g == 0) {
            uint4 o;
            o.x = (unsigned)f2b(a[0]) | ((unsigned)f2b(a[1]) << 16);
            o.y = (unsigned)f2b(a[2]) | ((unsigned)f2b(a[3]) << 16);
            o.z = (unsigned)f2b(a[4]) | ((unsigned)f2b(a[5]) << 16);
            o.w = (unsigned)f2b(a[6]) | ((unsigned)f2b(a[7]) << 16);
            *(uint4*)(msgb + (size_t)d * HID + l16 * 8) = o;
        }
    }
}

// ---------------- MFMA building blocks (M=64, 256 threads) ----------------

__device__ __forceinline__ void load_tile64(const u16* __restrict__ base, int tid, uint4 p[4]) {
#pragma unroll
    for (int q = 0; q < 4; q++) {
        int c = tid + q * 256;
        p[q] = *(const uint4*)(base + (size_t)(c >> 4) * HID + (c & 15) * 8);
    }
}

__device__ __forceinline__ void write_tile64(const uint4 p[4], int tid, u16* s) {
#pragma unroll
    for (int q = 0; q < 4; q++) {
        int c = tid + q * 256;
        *(uint4*)(s + (c >> 4) * LDST + (c & 15) * 8) = p[q];
    }
}

// A from LDS, B direct from global fragment layout (coalesced 1KB/wave-load, L2-hot)
__device__ __forceinline__ void macF(const u16* sA, const u16* __restrict__ Wf, int wrow, int half,
                                     int lane, int ln15, int quad, f32x4 acc[2][4]) {
    const u16* wb = Wf + (size_t)half * 8192;
#pragma unroll
    for (int kk = 0; kk < 4; kk++) {
        short8 a[2], b[4];
#pragma unroll
        for (int mi = 0; mi < 2; mi++)
            a[mi] = *(const short8*)(sA + (wrow + mi * 16 + ln15) * LDST + kk * 32 + quad * 8);
#pragma unroll
        for (int ni = 0; ni < 4; ni++)
            b[ni] = *(const short8*)(wb + (size_t)(((kk * 4 + ni) * 64) + lane) * 8);
#pragma unroll
        for (int mi = 0; mi < 2; mi++)
#pragma unroll
            for (int ni = 0; ni < 4; ni++)
                acc[mi][ni] = __builtin_amdgcn_mfma_f32_16x16x32_bf16(a[mi], b[ni], acc[mi][ni], 0, 0, 0);
    }
}

__device__ __forceinline__ void set_bias(f32x4 acc[2][4], const float* bias, int wcol, int ln15) {
#pragma unroll
    for (int ni = 0; ni < 4; ni++) {
        float bv = bias[wcol + ni * 16 + ln15];
#pragma unroll
        for (int mi = 0; mi < 2; mi++) acc[mi][ni] = (f32x4){bv, bv, bv, bv};
    }
}

__device__ __forceinline__ void acc_to_sA(const f32x4 acc[2][4], u16* sA, int wrow, int wcol,
                                          int ln15, int quad) {
#pragma unroll
    for (int mi = 0; mi < 2; mi++)
#pragma unroll
        for (int r = 0; r < 4; r++) {
            int row = wrow + mi * 16 + quad * 4 + r;
#pragma unroll
            for (int ni = 0; ni < 4; ni++)
                sA[row * LDST + wcol + ni * 16 + ln15] = f2b(fmaxf(acc[mi][ni][r], 0.f));
        }
}

// ---------------- fused fill2 + init MLP (2-buffer ping-pong) ----------------

__global__ __launch_bounds__(256) void f2init_k(const unsigned* __restrict__ ebuf, const int* __restrict__ bktbase,
                                                int* __restrict__ row_ptr, int* __restrict__ deg,
                                                int* __restrict__ srcs,
                                                const float* __restrict__ feat,
                                                const u16* __restrict__ W0f, const u16* __restrict__ W1f,
                                                const u16* __restrict__ W2f,
                                                const float* __restrict__ b0, const float* __restrict__ b1,
                                                const float* __restrict__ b2,
                                                float* __restrict__ h, u16* __restrict__ hb,
                                                float* __restrict__ gsum0, int n, int nbk) {
    __shared__ u16 s0[64 * LDST];
    __shared__ u16 s1[64 * LDST];
    int tid = threadIdx.x;
    if ((int)blockIdx.x < nbk) {
        // ---- fill2 part
        int* hist64 = (int*)s0;
        int* lofs = (int*)s0 + 64;
        int b = blockIdx.x;
        int e0 = bktbase[b], e1 = bktbase[b + 1];
        if (tid < 64) hist64[tid] = 0;
        __syncthreads();
        for (int i = e0 + tid; i < e1; i += 256) atomicAdd(&hist64[ebuf[i] >> 26], 1);
        __syncthreads();
        if (tid < 64) {
            int d = hist64[tid];
            int s = d;
#pragma unroll
            for (int off = 1; off < 64; off <<= 1) {
                int t = __shfl_up(s, off);
                if (tid >= off) s += t;
            }
            int excl = e0 + s - d;
            int gi = (b << NBSH) + tid;
            if (gi < n) { row_ptr[gi] = excl; deg[gi] = d; }
            lofs[tid] = excl;
        }
        __syncthreads();
        for (int i = e0 + tid; i < e1; i += 256) {
            unsigned p = ebuf[i];
            int d = (int)(p >> 26);
            int pos = atomicAdd(&lofs[d], 1);
            srcs[pos] = (int)(p & SRCM);
        }
        return;
    }
    // ---- init part (64-row tile, 2-buffer)
    int lane = tid & 63, wave = tid >> 6;
    int ln15 = lane & 15, quad = lane >> 4;
    int wrow = (wave >> 1) * 32, half = wave & 1, wcol = half * 64;
    int row0 = (blockIdx.x - nbk) * 64;
    f32x4 acc[2][4];

    {   // stage feat -> s0: 64 rows x 16 fp32 -> bf16 cols [0,16), zeros [16,32)
        int row = tid >> 2, coff = tid & 3;
        ushort4 o = make_ushort4(0, 0, 0, 0);
        if (row0 + row < n) {
            float4 v = *(const float4*)(feat + (size_t)(row0 + row) * IN_DIM + coff * 4);
            o = make_ushort4(f2b(v.x), f2b(v.y), f2b(v.z), f2b(v.w));
        }
        *(ushort4*)(s0 + row * LDST + coff * 4) = o;
        *(ushort4*)(s0 + row * LDST + 16 + coff * 4) = make_ushort4(0, 0, 0, 0);
    }
    set_bias(acc, b0, wcol, ln15);
    __syncthreads();                                  // B1: feat staged
    {   // layer0: K=32 (upper 16 zero-padded), B from W0 fragment
        short8 a[2], b[4];
#pragma unroll
        for (int mi = 0; mi < 2; mi++)
            a[mi] = *(const short8*)(s0 + (wrow + mi * 16 + ln15) * LDST + quad * 8);
#pragma unroll
        for (int ni = 0; ni < 4; ni++)
            b[ni] = *(const short8*)(W0f + (size_t)((half * 4 + ni) * 64 + lane) * 8);
#pragma unroll
        for (int mi = 0; mi < 2; mi++)
#pragma unroll
            for (int ni = 0; ni < 4; ni++)
                acc[mi][ni] = __builtin_amdgcn_mfma_f32_16x16x32_bf16(a[mi], b[ni], acc[mi][ni], 0, 0, 0);
    }
    acc_to_sA(acc, s1, wrow, wcol, ln15, quad);       // relu(l0) -> s1 (s1 untouched before)
    set_bias(acc, b1, wcol, ln15);
    __syncthreads();                                  // B2: s1 ready (also: everyone past l0-mac)
    macF(s1, W1f, wrow, half, lane, ln15, quad, acc);
    acc_to_sA(acc, s0, wrow, wcol, ln15, quad);       // relu(l1) -> s0 (free since B2)
    set_bias(acc, b2, wcol, ln15);
    __syncthreads();                                  // B3: s0 ready
    macF(s0, W2f, wrow, half, lane, ln15, quad, acc);

    // epilogue: h (fp32), hb (bf16), column-sum -> gsum0
    float csum[4] = {0.f, 0.f, 0.f, 0.f};
#pragma unroll
    for (int mi = 0; mi < 2; mi++)
#pragma unroll
        for (int r = 0; r < 4; r++) {
            int row = row0 + wrow + mi * 16 + quad * 4 + r;
            if (row < n) {
#pragma unroll
                for (int ni = 0; ni < 4; ni++) {
                    float v = acc[mi][ni][r];
                    int col = wcol + ni * 16 + ln15;
                    h[(size_t)row * HID + col] = v;
                    hb[(size_t)row * HID + col] = f2b(v);
                    csum[ni] += v;
                }
            }
        }
    __syncthreads();                                  // s1 free (last read macF W1)
    float* s_cs = (float*)s1;
    if (tid < HID) s_cs[tid] = 0.f;
    __syncthreads();
#pragma unroll
    for (int ni = 0; ni < 4; ni++) {
        float p = csum[ni];
        p += __shfl_xor(p, 16);
        p += __shfl_xor(p, 32);
        if (quad == 0) atomicAdd(&s_cs[wcol + ni * 16 + ln15], p);
    }
    __syncthreads();
    if (tid < HID) atomicAdd(&gsum0[tid], s_cs[tid]);
}

// ---------------- fused node update (r8: 2-buffer ping-pong, 7 barriers) ----------------

template <bool FINAL>
__global__ __launch_bounds__(256, 4) void node_fused_k(const u16* __restrict__ msgb, const u16* __restrict__ hbin,
                                                       const u16* __restrict__ W0af, const u16* __restrict__ W0bf,
                                                       const u16* __restrict__ W1f, const u16* __restrict__ W2f,
                                                       const float* __restrict__ grW,
                                                       const float* __restrict__ b1, const float* __restrict__ b2,
                                                       const int* __restrict__ deg,
                                                       float* __restrict__ h, u16* __restrict__ hb,
                                                       float* __restrict__ gsumOut, int n) {
    __shared__ u16 s0[64 * LDST];
    __shared__ u16 s1[64 * LDST];
    int tid = threadIdx.x;
    int lane = tid & 63, wave = tid >> 6;
    int ln15 = lane & 15, quad = lane >> 4;
    int wrow = (wave >> 1) * 32, half = wave & 1, wcol = half * 64;
    int row0 = blockIdx.x * 64;
    f32x4 acc[2][4];

    {   // stage BOTH inputs up front (independent; loads overlap)
        uint4 tM[4], tH[4];
        load_tile64(msgb + (size_t)row0 * HID, tid, tM);
        load_tile64(hbin + (size_t)row0 * HID, tid, tH);
        write_tile64(tM, tid, s0);
        write_tile64(tH, tid, s1);
    }
    set_bias(acc, grW, wcol, ln15);
    __syncthreads();                                  // B1: both tiles staged
    macF(s0, W0af, wrow, half, lane, ln15, quad, acc);
    macF(s1, W0bf, wrow, half, lane, ln15, quad, acc);
    __syncthreads();                                  // B2: everyone done reading s0,s1
    acc_to_sA(acc, s0, wrow, wcol, ln15, quad);       // relu(l0) -> s0
    set_bias(acc, b1, wcol, ln15);
    __syncthreads();                                  // B3: s0 ready
    macF(s0, W1f, wrow, half, lane, ln15, quad, acc);
    acc_to_sA(acc, s1, wrow, wcol, ln15, quad);       // relu(l1) -> s1 (free since B2)
    set_bias(acc, b2, wcol, ln15);
    __syncthreads();                                  // B4: s1 ready
    macF(s1, W2f, wrow, half, lane, ln15, quad, acc);

    // epilogue: rownorm + conditional update + gsum (scratch in s0: free after B4+W1 done)
    __syncthreads();                                  // B5: W1-mac readers of s0 all past
    float* s_rs = (float*)s0;
    float* s_cs = (float*)s0 + 64;
    if (tid < 64) s_rs[tid] = 0.f;
    else if (tid < 192) s_cs[tid - 64] = 0.f;
    __syncthreads();                                  // B6
#pragma unroll
    for (int mi = 0; mi < 2; mi++)
#pragma unroll
        for (int r = 0; r < 4; r++) {
            float p = 0.f;
#pragma unroll
            for (int ni = 0; ni < 4; ni++) { float v = acc[mi][ni][r]; p += v * v; }
            p += __shfl_xor(p, 1); p += __shfl_xor(p, 2);
            p += __shfl_xor(p, 4); p += __shfl_xor(p, 8);
            if (ln15 == 0) atomicAdd(&s_rs[wrow + mi * 16 + quad * 4 + r], p);
        }
    __syncthreads();                                  // B7
    float csum[4] = {0.f, 0.f, 0.f, 0.f};
#pragma unroll
    for (int mi = 0; mi < 2; mi++)
#pragma unroll
        for (int r = 0; r < 4; r++) {
            int rl = wrow + mi * 16 + quad * 4 + r;
            int row = row0 + rl;
            if (row < n) {
                bool upd = deg[row] > 0;
                float inv = 1.f / (sqrtf(s_rs[rl]) + 1e-8f);
#pragma unroll
                for (int ni = 0; ni < 4; ni++) {
                    int col = wcol + ni * 16 + ln15;
                    if (FINAL) {
                        if (upd) h[(size_t)row * HID + col] = acc[mi][ni][r] * inv;
                    } else {
                        float v;
                        if (upd) {
                            v = acc[mi][ni][r] * inv;
                            hb[(size_t)row * HID + col] = f2b(v);
                        } else {
                            v = h[(size_t)row * HID + col];
                        }
                        csum[ni] += v;
                    }
                }
            }
        }
    if (!FINAL) {
#pragma unroll
        for (int ni = 0; ni < 4; ni++) {
            float p = csum[ni];
            p += __shfl_xor(p, 16);
            p += __shfl_xor(p, 32);
            if (quad == 0) atomicAdd(&s_cs[wcol + ni * 16 + ln15], p);
        }
        __syncthreads();
        if (tid < HID) atomicAdd(&gsumOut[tid], s_cs[tid]);
    }
}

// ---------------- launch ----------------

static inline char* align_up(char* p, size_t a) {
    return (char*)(((uintptr_t)p + a - 1) & ~(uintptr_t)(a - 1));
}

extern "C" void kernel_launch(void* const* d_in, const int* in_sizes, int n_in,
                              void* d_out, int out_size, void* d_ws, size_t ws_size,
                              hipStream_t stream) {
    const float* feat = (const float*)d_in[0];
    const int* src = (const int*)d_in[1];
    const int* dst = (const int*)d_in[2];
    const float* iW0 = (const float*)d_in[3];
    const float* ib0 = (const float*)d_in[4];
    const float* iW1 = (const float*)d_in[5];
    const float* ib1 = (const float*)d_in[6];
    const float* iW2 = (const float*)d_in[7];
    const float* ib2 = (const float*)d_in[8];
    const float* nW0 = (const float*)d_in[9];
    const float* nb0 = (const float*)d_in[10];
    const float* nW1 = (const float*)d_in[11];
    const float* nb1 = (const float*)d_in[12];
    const float* nW2 = (const float*)d_in[13];
    const float* nb2 = (const float*)d_in[14];

    int N = in_sizes[0] / IN_DIM;
    int E = in_sizes[1];
    int n_iter = in_sizes[10] / HID;
    int NB = (N + (1 << NBSH) - 1) >> NBSH;
    float* h = (float*)d_out;

    char* w = (char*)d_ws;
    size_t big2 = (size_t)(N + 128) * HID * sizeof(u16);
    u16* hb   = (u16*)w; w += big2;
    u16* msgb = (u16*)w; w += big2;
    float* gsums = (float*)w; w += (size_t)(n_iter + 1) * HID * sizeof(float);
    float* grW = (float*)w; w += 1024;
    u16* Wt = (u16*)w; w += (size_t)(4096 + 2 * 16384 + n_iter * 4 * 16384) * sizeof(u16);
    w = align_up(w, 16);
    int* deg = (int*)w; w += (size_t)N * 4;  w = align_up(w, 16);
    int* row_ptr = (int*)w; w += (size_t)(N + 1) * 4;  w = align_up(w, 16);
    int* bktcnt = (int*)w; w += (size_t)NB * 4;  w = align_up(w, 16);
    int* bktbase = (int*)w; w += (size_t)(NB + 1) * 4;  w = align_up(w, 64);
    int* bcnt = (int*)w; w += (size_t)NB * BPAD * 4;  w = align_up(w, 16);
    int* srcs = (int*)w; w += (size_t)E * 4;  w = align_up(w, 16);
    unsigned* ebuf = (unsigned*)w; w += (size_t)E * 4;
    (void)ws_size; (void)n_in; (void)out_size;

    const int OFF_IW0 = 0;                       // 4096 shorts (K=32 fragment)
    const int OFF_IW1 = 4096;
    const int OFF_IW2 = 4096 + 16384;
    const int OFF_IT = 4096 + 2 * 16384;

    WJobs jobs;
    int nj = 0;
    jobs.src[nj] = iW0; jobs.dstoff[nj] = OFF_IW0; jobs.ks[nj] = 5; nj++;
    jobs.src[nj] = iW1; jobs.dstoff[nj] = OFF_IW1; jobs.ks[nj] = 8; nj++;
    jobs.src[nj] = iW2; jobs.dstoff[nj] = OFF_IW2; jobs.ks[nj] = 8; nj++;
    for (int i = 0; i < n_iter && nj + 4 <= 16; i++) {
        int base = OFF_IT + i * 4 * 16384;
        jobs.src[nj] = nW0 + (size_t)i * 3 * HID * HID;               jobs.dstoff[nj] = base;             jobs.ks[nj] = 8; nj++;
        jobs.src[nj] = nW0 + (size_t)i * 3 * HID * HID + HID * HID;   jobs.dstoff[nj] = base + 16384;     jobs.ks[nj] = 8; nj++;
        jobs.src[nj] = nW1 + (size_t)i * HID * HID;                   jobs.dstoff[nj] = base + 2 * 16384; jobs.ks[nj] = 8; nj++;
        jobs.src[nj] = nW2 + (size_t)i * HID * HID;                   jobs.dstoff[nj] = base + 3 * 16384; jobs.ks[nj] = 8; nj++;
    }

    hipMemsetAsync(bktcnt, 0, (size_t)NB * 4, stream);  // must precede preph's hist part

    int cg = (E + CH - 1) / CH;
    preph_k<<<nj + cg, 256, 0, stream>>>(jobs, Wt, dst, bktcnt,
                                         gsums, (n_iter + 1) * HID, E, NB, nj);
    bscan_k<<<1, 1024, 0, stream>>>(bktcnt, bktbase, bcnt, row_ptr, NB, N, E);
    int cgb = (E + CHB - 1) / CHB;
    bin_k<<<cgb, 256, 0, stream>>>(src, dst, bcnt, ebuf, E, NB);

    int gbi = (N + 63) / 64;
    f2init_k<<<NB + gbi, 256, 0, stream>>>(ebuf, bktbase, row_ptr, deg, srcs,
                                           feat, Wt + OFF_IW0, Wt + OFF_IW1, Wt + OFF_IW2,
                                           ib0, ib1, ib2, h, hb, gsums, N, NB);

    int gb2 = (N + 63) / 64;
    int dpb = 4 * NDPW;
    int rb = (N + dpb - 1) / dpb;
    for (int i = 0; i < n_iter; i++) {
        const u16* Wit = Wt + OFF_IT + (size_t)i * 4 * 16384;
        const float* Wg = nW0 + (size_t)i * 3 * HID * HID + 2 * HID * HID;
        msg_k<<<rb + 1, 256, 0, stream>>>(hb, row_ptr, srcs, msgb, N,
                                          gsums + (size_t)i * HID, Wg, nb0 + (size_t)i * HID, grW);
        if (i + 1 < n_iter) {
            node_fused_k<false><<<gb2, 256, 0, stream>>>(msgb, hb, Wit, Wit + 16384, Wit + 2 * 16384,
                                                         Wit + 3 * 16384, grW, nb1 + (size_t)i * HID,
                                                         nb2 + (size_t)i * HID, deg, h, hb,
                                                         gsums + (size_t)(i + 1) * HID, N);
        } else {
            node_fused_k<true><<<gb2, 256, 0, stream>>>(msgb, hb, Wit, Wit + 16384, Wit + 2 * 16384,
                                                        Wit + 3 * 16384, grW, nb1 + (size_t)i * HID,
                                                        nb2 + (size_t)i * HID, deg, h, hb,
                                                        nullptr, N);
        }
    }
}

// Round 13
// 407.580 us; speedup vs baseline: 1.0795x; 1.0795x over previous
//
#include <hip/hip_runtime.h>
#include <hip/hip_bf16.h>

#define HID 128
#define IN_DIM 16
#define LDST 136   // LDS row stride in bf16 elems (272 B)
#define NBSH 6     // bucket = dst >> 6  (64 dsts/bucket)
#define BPAD 16    // bucket counter padding (ints) -> one 64B line per counter
#define SRCM 0x3ffffffu
#define CH 8192    // edges per chunk (preph hist / bin_k)
#define NBMAX 1024
#define NDPW 4     // sequential dsts per wave in msg_k

typedef unsigned short u16;
typedef __attribute__((ext_vector_type(8))) short short8;
typedef __attribute__((ext_vector_type(4))) float f32x4;

__device__ __forceinline__ u16 f2b(float f) {  // RNE
    unsigned u = __float_as_uint(f);
    return (u16)((u + 0x7FFF + ((u >> 16) & 1)) >> 16);
}

// ---------------- graph prep ----------------

__global__ __launch_bounds__(1024) void bscan_k(const int* __restrict__ bktcnt, int* __restrict__ bktbase,
                                                int* __restrict__ bcnt, int* __restrict__ row_ptr,
                                                int nb, int n, int E) {
    __shared__ int sbuf[1024];
    int t = threadIdx.x;
    int v = (t < nb) ? bktcnt[t] : 0;
    sbuf[t] = v;
    __syncthreads();
    for (int off = 1; off < 1024; off <<= 1) {
        int a = (t >= off) ? sbuf[t - off] : 0;
        __syncthreads();
        sbuf[t] += a;
        __syncthreads();
    }
    if (t < nb) {
        int excl = sbuf[t] - v;
        bktbase[t] = excl;
        bcnt[t * BPAD] = excl;
    }
    if (t == 0) { bktbase[nb] = E; row_ptr[n] = E; }
}

// r12: CH=8192 chunks (196 blocks, big coalesced bucket segments — r11's CHB=2048
// amplified writes 2.6x and quadrupled fixed work) but 1024 THREADS/block: every
// per-thread loop is 4x shorter and 16 waves hide LDS-atomic/barrier latency.
__global__ __launch_bounds__(1024) void bin_k(const int* __restrict__ src, const int* __restrict__ dst,
                                              int* __restrict__ bcnt, unsigned* __restrict__ ebuf,
                                              int E, int nb) {
    __shared__ unsigned stage[CH];     // 32 KB
    __shared__ u16 sbk[CH];            // 16 KB
    __shared__ int hist[NBMAX];        // 4 KB
    __shared__ int lofs[NBMAX];        // 4 KB
    __shared__ int sbase[NBMAX];       // 4 KB
    __shared__ int sscan[1024];        // 4 KB
    int tid = threadIdx.x;
    int base = blockIdx.x * CH;
    int cnt = E - base; if (cnt > CH) cnt = CH;

    for (int i = tid; i < nb; i += 1024) hist[i] = 0;
    __syncthreads();
    for (int j = tid; j < cnt; j += 1024) atomicAdd(&hist[dst[base + j] >> NBSH], 1);
    __syncthreads();
    // 1024-thread Hillis-Steele inclusive scan over buckets (nb <= 1024)
    int v = (tid < nb) ? hist[tid] : 0;
    sscan[tid] = v;
    __syncthreads();
    for (int off = 1; off < 1024; off <<= 1) {
        int a = (tid >= off) ? sscan[tid - off] : 0;
        __syncthreads();
        sscan[tid] += a;
        __syncthreads();
    }
    if (tid < nb) lofs[tid] = sscan[tid] - v;   // exclusive prefix
    __syncthreads();
    for (int i = tid; i < nb; i += 1024) {
        int c = hist[i];
        if (c > 0) {
            int g = atomicAdd(&bcnt[i * BPAD], c);
            sbase[i] = g - lofs[i];
        }
    }
    __syncthreads();
    for (int j = tid; j < cnt; j += 1024) {
        int e = base + j;
        int d = dst[e];
        int b = d >> NBSH;
        int r = atomicAdd(&lofs[b], 1);
        stage[r] = (unsigned)src[e] | ((unsigned)(d & 63) << 26);
        sbk[r] = (u16)b;
    }
    __syncthreads();
    for (int s = tid; s < cnt; s += 1024) {
        int b = sbk[s];
        ebuf[sbase[b] + s] = stage[s];
    }
}

// ---------------- fused weight prep + histogram + zeroing ----------------
// blocks [0,nj): weight jobs (block 0 also zeros gsums);
// blocks [nj,nj+cg): dst histogram chunks (CH=8192 each).
// ks==5: fp32 [16,128] -> K=32 zero-padded MFMA B-fragment [half][ni][lane][8]
// ks==8: fp32 [128,128] -> MFMA B-fragment [half][kk][ni][lane][8]
//        elem j of lane (quad,ln15) = W[kk*32+quad*8+j][half*64+ni*16+ln15].

struct WJobs {
    const float* src[16];
    int dstoff[16];
    int ks[16];
};

__global__ __launch_bounds__(256) void preph_k(WJobs j, u16* __restrict__ Wt,
                                               const int* __restrict__ dst, int* __restrict__ bktcnt,
                                               float* __restrict__ gsums, int gz,
                                               int E, int nb, int nj) {
    __shared__ int hist[NBMAX];
    int tid = threadIdx.x;
    if ((int)blockIdx.x >= nj) {
        int base = (blockIdx.x - nj) * CH;
        int cnt = E - base; if (cnt > CH) cnt = CH;
        for (int i = tid; i < nb; i += 256) hist[i] = 0;
        __syncthreads();
        for (int jx = tid; jx < cnt; jx += 256) atomicAdd(&hist[dst[base + jx] >> NBSH], 1);
        __syncthreads();
        for (int i = tid; i < nb; i += 256) {
            int c = hist[i];
            if (c > 0) atomicAdd(&bktcnt[i], c);
        }
        return;
    }
    int m = blockIdx.x;
    if (m == 0) {
        for (int i = tid; i < gz; i += 256) gsums[i] = 0.f;
    }
    const float* s = j.src[m];
    u16* d = Wt + j.dstoff[m];
    if (j.ks[m] == 5) {  // W0: 16x128, K padded to 32 with zeros
        for (int idx = tid; idx < 4096; idx += 256) {
            int jj = idx & 7;
            int lane = (idx >> 3) & 63;
            int ni = (idx >> 9) & 3;
            int half = (idx >> 11) & 1;
            int k = ((lane >> 4) << 3) + jj;
            int col = half * 64 + ni * 16 + (lane & 15);
            d[idx] = (k < IN_DIM) ? f2b(s[k * HID + col]) : (u16)0;
        }
    } else {  // ks==8: 128x128
        for (int idx = tid; idx < 16384; idx += 256) {
            int jj = idx & 7;
            int lane = (idx >> 3) & 63;
            int ni = (idx >> 9) & 3;
            int kk = (idx >> 11) & 3;
            int half = idx >> 13;
            int k = kk * 32 + (lane >> 4) * 8 + jj;
            int col = half * 64 + ni * 16 + (lane & 15);
            d[idx] = f2b(s[k * HID + col]);
        }
    }
}

// ---------------- message aggregation (r4-proven, unchanged) ----------------

__device__ __forceinline__ void unpack_add(uint4 v, float* a) {
    a[0] += __uint_as_float(v.x << 16);
    a[1] += __uint_as_float(v.x & 0xffff0000u);
    a[2] += __uint_as_float(v.y << 16);
    a[3] += __uint_as_float(v.y & 0xffff0000u);
    a[4] += __uint_as_float(v.z << 16);
    a[5] += __uint_as_float(v.z & 0xffff0000u);
    a[6] += __uint_as_float(v.w << 16);
    a[7] += __uint_as_float(v.w & 0xffff0000u);
}

__global__ __launch_bounds__(256) void msg_k(const u16* __restrict__ hb, const int* __restrict__ row_ptr,
                                             const int* __restrict__ srcs, u16* __restrict__ msgb, int n,
                                             const float* __restrict__ gsumIn, const float* __restrict__ Wg,
                                             const float* __restrict__ b0, float* __restrict__ grW) {
    if (blockIdx.x == gridDim.x - 1) {
        __shared__ float sred[2];
        __shared__ float sgr[HID];
        int t = threadIdx.x;
        if (t < HID) {
            float g = gsumIn[t];
            float s = g * g;
#pragma unroll
            for (int off = 1; off < 64; off <<= 1) s += __shfl_xor(s, off);
            if ((t & 63) == 0) sred[t >> 6] = s;
        }
        __syncthreads();
        if (t < HID) {
            float inv = 1.f / (sqrtf(sred[0] + sred[1]) + 1e-8f);
            sgr[t] = gsumIn[t] * inv;
        }
        __syncthreads();
        if (t < HID) {
            float a = b0[t];
#pragma unroll 4
            for (int k = 0; k < HID; k++) a += sgr[k] * Wg[k * HID + t];
            grW[t] = a;
        }
        return;
    }
    int wave = threadIdx.x >> 6, lane = threadIdx.x & 63;
    int g = lane >> 4;
    int l16 = lane & 15;
    int d0 = (blockIdx.x * 4 + wave) * NDPW;
    if (d0 >= n) return;
    int eNext = row_ptr[d0];
#pragma unroll 1
    for (int k = 0; k < NDPW; k++) {
        int d = d0 + k;
        if (d >= n) break;
        int e = eNext;
        int e1 = row_ptr[d + 1];
        eNext = e1;
        float a[8] = {0.f, 0.f, 0.f, 0.f, 0.f, 0.f, 0.f, 0.f};
        int s0 = 0, s1 = 0, s2 = 0, s3 = 0;
        if (e + 15 < e1) {
            s0 = srcs[e + g]; s1 = srcs[e + 4 + g];
            s2 = srcs[e + 8 + g]; s3 = srcs[e + 12 + g];
        }
        while (e + 15 < e1) {
            int t0 = s0, t1 = s1, t2 = s2, t3 = s3;
            int en = e + 16;
            if (en + 15 < e1) {
                s0 = srcs[en + g]; s1 = srcs[en + 4 + g];
                s2 = srcs[en + 8 + g]; s3 = srcs[en + 12 + g];
            }
            uint4 v0 = *(const uint4*)(hb + (size_t)t0 * HID + l16 * 8);
            uint4 v1 = *(const uint4*)(hb + (size_t)t1 * HID + l16 * 8);
            uint4 v2 = *(const uint4*)(hb + (size_t)t2 * HID + l16 * 8);
            uint4 v3 = *(const uint4*)(hb + (size_t)t3 * HID + l16 * 8);
            unpack_add(v0, a);
            unpack_add(v1, a);
            unpack_add(v2, a);
            unpack_add(v3, a);
            e = en;
        }
        if (e + 7 < e1) {
            int t0 = srcs[e + g], t1 = srcs[e + 4 + g];
            uint4 v0 = *(const uint4*)(hb + (size_t)t0 * HID + l16 * 8);
            uint4 v1 = *(const uint4*)(hb + (size_t)t1 * HID + l16 * 8);
            unpack_add(v0, a);
            unpack_add(v1, a);
            e += 8;
        }
        if (e + 3 < e1) {
            int s = srcs[e + g];
            uint4 v = *(const uint4*)(hb + (size_t)s * HID + l16 * 8);
            unpack_add(v, a);
            e += 4;
        }
        if (e + g < e1) {
            int s = srcs[e + g];
            uint4 v = *(const uint4*)(hb + (size_t)s * HID + l16 * 8);
            unpack_add(v, a);
        }
#pragma unroll
        for (int i = 0; i < 8; i++) {
            a[i] += __shfl_xor(a[i], 16);
            a[i] += __shfl_xor(a[i], 32);
        }
        if (g == 0) {
            uint4 o;
            o.x = (unsigned)f2b(a[0]) | ((unsigned)f2b(a[1]) << 16);
            o.y = (unsigned)f2b(a[2]) | ((unsigned)f2b(a[3]) << 16);
            o.z = (unsigned)f2b(a[4]) | ((unsigned)f2b(a[5]) << 16);
            o.w = (unsigned)f2b(a[6]) | ((unsigned)f2b(a[7]) << 16);
            *(uint4*)(msgb + (size_t)d * HID + l16 * 8) = o;
        }
    }
}

// ---------------- MFMA building blocks (M=64, 256 threads) ----------------

__device__ __forceinline__ void load_tile64(const u16* __restrict__ base, int tid, uint4 p[4]) {
#pragma unroll
    for (int q = 0; q < 4; q++) {
        int c = tid + q * 256;
        p[q] = *(const uint4*)(base + (size_t)(c >> 4) * HID + (c & 15) * 8);
    }
}

__device__ __forceinline__ void write_tile64(const uint4 p[4], int tid, u16* s) {
#pragma unroll
    for (int q = 0; q < 4; q++) {
        int c = tid + q * 256;
        *(uint4*)(s + (c >> 4) * LDST + (c & 15) * 8) = p[q];
    }
}

// A from LDS, B direct from global fragment layout (coalesced 1KB/wave-load, L2-hot)
__device__ __forceinline__ void macF(const u16* sA, const u16* __restrict__ Wf, int wrow, int half,
                                     int lane, int ln15, int quad, f32x4 acc[2][4]) {
    const u16* wb = Wf + (size_t)half * 8192;
#pragma unroll
    for (int kk = 0; kk < 4; kk++) {
        short8 a[2], b[4];
#pragma unroll
        for (int mi = 0; mi < 2; mi++)
            a[mi] = *(const short8*)(sA + (wrow + mi * 16 + ln15) * LDST + kk * 32 + quad * 8);
#pragma unroll
        for (int ni = 0; ni < 4; ni++)
            b[ni] = *(const short8*)(wb + (size_t)(((kk * 4 + ni) * 64) + lane) * 8);
#pragma unroll
        for (int mi = 0; mi < 2; mi++)
#pragma unroll
            for (int ni = 0; ni < 4; ni++)
                acc[mi][ni] = __builtin_amdgcn_mfma_f32_16x16x32_bf16(a[mi], b[ni], acc[mi][ni], 0, 0, 0);
    }
}

__device__ __forceinline__ void set_bias(f32x4 acc[2][4], const float* bias, int wcol, int ln15) {
#pragma unroll
    for (int ni = 0; ni < 4; ni++) {
        float bv = bias[wcol + ni * 16 + ln15];
#pragma unroll
        for (int mi = 0; mi < 2; mi++) acc[mi][ni] = (f32x4){bv, bv, bv, bv};
    }
}

__device__ __forceinline__ void acc_to_sA(const f32x4 acc[2][4], u16* sA, int wrow, int wcol,
                                          int ln15, int quad) {
#pragma unroll
    for (int mi = 0; mi < 2; mi++)
#pragma unroll
        for (int r = 0; r < 4; r++) {
            int row = wrow + mi * 16 + quad * 4 + r;
#pragma unroll
            for (int ni = 0; ni < 4; ni++)
                sA[row * LDST + wcol + ni * 16 + ln15] = f2b(fmaxf(acc[mi][ni][r], 0.f));
        }
}

// ---------------- fused fill2 + init MLP (2-buffer ping-pong) ----------------

__global__ __launch_bounds__(256) void f2init_k(const unsigned* __restrict__ ebuf, const int* __restrict__ bktbase,
                                                int* __restrict__ row_ptr, int* __restrict__ deg,
                                                int* __restrict__ srcs,
                                                const float* __restrict__ feat,
                                                const u16* __restrict__ W0f, const u16* __restrict__ W1f,
                                                const u16* __restrict__ W2f,
                                                const float* __restrict__ b0, const float* __restrict__ b1,
                                                const float* __restrict__ b2,
                                                float* __restrict__ h, u16* __restrict__ hb,
                                                float* __restrict__ gsum0, int n, int nbk) {
    __shared__ u16 s0[64 * LDST];
    __shared__ u16 s1[64 * LDST];
    int tid = threadIdx.x;
    if ((int)blockIdx.x < nbk) {
        // ---- fill2 part
        int* hist64 = (int*)s0;
        int* lofs = (int*)s0 + 64;
        int b = blockIdx.x;
        int e0 = bktbase[b], e1 = bktbase[b + 1];
        if (tid < 64) hist64[tid] = 0;
        __syncthreads();
        for (int i = e0 + tid; i < e1; i += 256) atomicAdd(&hist64[ebuf[i] >> 26], 1);
        __syncthreads();
        if (tid < 64) {
            int d = hist64[tid];
            int s = d;
#pragma unroll
            for (int off = 1; off < 64; off <<= 1) {
                int t = __shfl_up(s, off);
                if (tid >= off) s += t;
            }
            int excl = e0 + s - d;
            int gi = (b << NBSH) + tid;
            if (gi < n) { row_ptr[gi] = excl; deg[gi] = d; }
            lofs[tid] = excl;
        }
        __syncthreads();
        for (int i = e0 + tid; i < e1; i += 256) {
            unsigned p = ebuf[i];
            int d = (int)(p >> 26);
            int pos = atomicAdd(&lofs[d], 1);
            srcs[pos] = (int)(p & SRCM);
        }
        return;
    }
    // ---- init part (64-row tile, 2-buffer)
    int lane = tid & 63, wave = tid >> 6;
    int ln15 = lane & 15, quad = lane >> 4;
    int wrow = (wave >> 1) * 32, half = wave & 1, wcol = half * 64;
    int row0 = (blockIdx.x - nbk) * 64;
    f32x4 acc[2][4];

    {   // stage feat -> s0: 64 rows x 16 fp32 -> bf16 cols [0,16), zeros [16,32)
        int row = tid >> 2, coff = tid & 3;
        ushort4 o = make_ushort4(0, 0, 0, 0);
        if (row0 + row < n) {
            float4 v = *(const float4*)(feat + (size_t)(row0 + row) * IN_DIM + coff * 4);
            o = make_ushort4(f2b(v.x), f2b(v.y), f2b(v.z), f2b(v.w));
        }
        *(ushort4*)(s0 + row * LDST + coff * 4) = o;
        *(ushort4*)(s0 + row * LDST + 16 + coff * 4) = make_ushort4(0, 0, 0, 0);
    }
    set_bias(acc, b0, wcol, ln15);
    __syncthreads();                                  // B1: feat staged
    {   // layer0: K=32 (upper 16 zero-padded), B from W0 fragment
        short8 a[2], b[4];
#pragma unroll
        for (int mi = 0; mi < 2; mi++)
            a[mi] = *(const short8*)(s0 + (wrow + mi * 16 + ln15) * LDST + quad * 8);
#pragma unroll
        for (int ni = 0; ni < 4; ni++)
            b[ni] = *(const short8*)(W0f + (size_t)((half * 4 + ni) * 64 + lane) * 8);
#pragma unroll
        for (int mi = 0; mi < 2; mi++)
#pragma unroll
            for (int ni = 0; ni < 4; ni++)
                acc[mi][ni] = __builtin_amdgcn_mfma_f32_16x16x32_bf16(a[mi], b[ni], acc[mi][ni], 0, 0, 0);
    }
    acc_to_sA(acc, s1, wrow, wcol, ln15, quad);       // relu(l0) -> s1 (s1 untouched before)
    set_bias(acc, b1, wcol, ln15);
    __syncthreads();                                  // B2: s1 ready (also: everyone past l0-mac)
    macF(s1, W1f, wrow, half, lane, ln15, quad, acc);
    acc_to_sA(acc, s0, wrow, wcol, ln15, quad);       // relu(l1) -> s0 (free since B2)
    set_bias(acc, b2, wcol, ln15);
    __syncthreads();                                  // B3: s0 ready
    macF(s0, W2f, wrow, half, lane, ln15, quad, acc);

    // epilogue: h (fp32), hb (bf16), column-sum -> gsum0
    float csum[4] = {0.f, 0.f, 0.f, 0.f};
#pragma unroll
    for (int mi = 0; mi < 2; mi++)
#pragma unroll
        for (int r = 0; r < 4; r++) {
            int row = row0 + wrow + mi * 16 + quad * 4 + r;
            if (row < n) {
#pragma unroll
                for (int ni = 0; ni < 4; ni++) {
                    float v = acc[mi][ni][r];
                    int col = wcol + ni * 16 + ln15;
                    h[(size_t)row * HID + col] = v;
                    hb[(size_t)row * HID + col] = f2b(v);
                    csum[ni] += v;
                }
            }
        }
    __syncthreads();                                  // s1 free (last read macF W1)
    float* s_cs = (float*)s1;
    if (tid < HID) s_cs[tid] = 0.f;
    __syncthreads();
#pragma unroll
    for (int ni = 0; ni < 4; ni++) {
        float p = csum[ni];
        p += __shfl_xor(p, 16);
        p += __shfl_xor(p, 32);
        if (quad == 0) atomicAdd(&s_cs[wcol + ni * 16 + ln15], p);
    }
    __syncthreads();
    if (tid < HID) atomicAdd(&gsum0[tid], s_cs[tid]);
}

// ---------------- fused node update (r8: 2-buffer ping-pong, 7 barriers) ----------------

template <bool FINAL>
__global__ __launch_bounds__(256, 4) void node_fused_k(const u16* __restrict__ msgb, const u16* __restrict__ hbin,
                                                       const u16* __restrict__ W0af, const u16* __restrict__ W0bf,
                                                       const u16* __restrict__ W1f, const u16* __restrict__ W2f,
                                                       const float* __restrict__ grW,
                                                       const float* __restrict__ b1, const float* __restrict__ b2,
                                                       const int* __restrict__ deg,
                                                       float* __restrict__ h, u16* __restrict__ hb,
                                                       float* __restrict__ gsumOut, int n) {
    __shared__ u16 s0[64 * LDST];
    __shared__ u16 s1[64 * LDST];
    int tid = threadIdx.x;
    int lane = tid & 63, wave = tid >> 6;
    int ln15 = lane & 15, quad = lane >> 4;
    int wrow = (wave >> 1) * 32, half = wave & 1, wcol = half * 64;
    int row0 = blockIdx.x * 64;
    f32x4 acc[2][4];

    {   // stage BOTH inputs up front (independent; loads overlap)
        uint4 tM[4], tH[4];
        load_tile64(msgb + (size_t)row0 * HID, tid, tM);
        load_tile64(hbin + (size_t)row0 * HID, tid, tH);
        write_tile64(tM, tid, s0);
        write_tile64(tH, tid, s1);
    }
    set_bias(acc, grW, wcol, ln15);
    __syncthreads();                                  // B1: both tiles staged
    macF(s0, W0af, wrow, half, lane, ln15, quad, acc);
    macF(s1, W0bf, wrow, half, lane, ln15, quad, acc);
    __syncthreads();                                  // B2: everyone done reading s0,s1
    acc_to_sA(acc, s0, wrow, wcol, ln15, quad);       // relu(l0) -> s0
    set_bias(acc, b1, wcol, ln15);
    __syncthreads();                                  // B3: s0 ready
    macF(s0, W1f, wrow, half, lane, ln15, quad, acc);
    acc_to_sA(acc, s1, wrow, wcol, ln15, quad);       // relu(l1) -> s1 (free since B2)
    set_bias(acc, b2, wcol, ln15);
    __syncthreads();                                  // B4: s1 ready
    macF(s1, W2f, wrow, half, lane, ln15, quad, acc);

    // epilogue: rownorm + conditional update + gsum (scratch in s0: free after B4+W1 done)
    __syncthreads();                                  // B5: W1-mac readers of s0 all past
    float* s_rs = (float*)s0;
    float* s_cs = (float*)s0 + 64;
    if (tid < 64) s_rs[tid] = 0.f;
    else if (tid < 192) s_cs[tid - 64] = 0.f;
    __syncthreads();                                  // B6
#pragma unroll
    for (int mi = 0; mi < 2; mi++)
#pragma unroll
        for (int r = 0; r < 4; r++) {
            float p = 0.f;
#pragma unroll
            for (int ni = 0; ni < 4; ni++) { float v = acc[mi][ni][r]; p += v * v; }
            p += __shfl_xor(p, 1); p += __shfl_xor(p, 2);
            p += __shfl_xor(p, 4); p += __shfl_xor(p, 8);
            if (ln15 == 0) atomicAdd(&s_rs[wrow + mi * 16 + quad * 4 + r], p);
        }
    __syncthreads();                                  // B7
    float csum[4] = {0.f, 0.f, 0.f, 0.f};
#pragma unroll
    for (int mi = 0; mi < 2; mi++)
#pragma unroll
        for (int r = 0; r < 4; r++) {
            int rl = wrow + mi * 16 + quad * 4 + r;
            int row = row0 + rl;
            if (row < n) {
                bool upd = deg[row] > 0;
                float inv = 1.f / (sqrtf(s_rs[rl]) + 1e-8f);
#pragma unroll
                for (int ni = 0; ni < 4; ni++) {
                    int col = wcol + ni * 16 + ln15;
                    if (FINAL) {
                        if (upd) h[(size_t)row * HID + col] = acc[mi][ni][r] * inv;
                    } else {
                        float v;
                        if (upd) {
                            v = acc[mi][ni][r] * inv;
                            hb[(size_t)row * HID + col] = f2b(v);
                        } else {
                            v = h[(size_t)row * HID + col];
                        }
                        csum[ni] += v;
                    }
                }
            }
        }
    if (!FINAL) {
#pragma unroll
        for (int ni = 0; ni < 4; ni++) {
            float p = csum[ni];
            p += __shfl_xor(p, 16);
            p += __shfl_xor(p, 32);
            if (quad == 0) atomicAdd(&s_cs[wcol + ni * 16 + ln15], p);
        }
        __syncthreads();
        if (tid < HID) atomicAdd(&gsumOut[tid], s_cs[tid]);
    }
}

// ---------------- launch ----------------

static inline char* align_up(char* p, size_t a) {
    return (char*)(((uintptr_t)p + a - 1) & ~(uintptr_t)(a - 1));
}

extern "C" void kernel_launch(void* const* d_in, const int* in_sizes, int n_in,
                              void* d_out, int out_size, void* d_ws, size_t ws_size,
                              hipStream_t stream) {
    const float* feat = (const float*)d_in[0];
    const int* src = (const int*)d_in[1];
    const int* dst = (const int*)d_in[2];
    const float* iW0 = (const float*)d_in[3];
    const float* ib0 = (const float*)d_in[4];
    const float* iW1 = (const float*)d_in[5];
    const float* ib1 = (const float*)d_in[6];
    const float* iW2 = (const float*)d_in[7];
    const float* ib2 = (const float*)d_in[8];
    const float* nW0 = (const float*)d_in[9];
    const float* nb0 = (const float*)d_in[10];
    const float* nW1 = (const float*)d_in[11];
    const float* nb1 = (const float*)d_in[12];
    const float* nW2 = (const float*)d_in[13];
    const float* nb2 = (const float*)d_in[14];

    int N = in_sizes[0] / IN_DIM;
    int E = in_sizes[1];
    int n_iter = in_sizes[10] / HID;
    int NB = (N + (1 << NBSH) - 1) >> NBSH;
    float* h = (float*)d_out;

    char* w = (char*)d_ws;
    size_t big2 = (size_t)(N + 128) * HID * sizeof(u16);
    u16* hb   = (u16*)w; w += big2;
    u16* msgb = (u16*)w; w += big2;
    float* gsums = (float*)w; w += (size_t)(n_iter + 1) * HID * sizeof(float);
    float* grW = (float*)w; w += 1024;
    u16* Wt = (u16*)w; w += (size_t)(4096 + 2 * 16384 + n_iter * 4 * 16384) * sizeof(u16);
    w = align_up(w, 16);
    int* deg = (int*)w; w += (size_t)N * 4;  w = align_up(w, 16);
    int* row_ptr = (int*)w; w += (size_t)(N + 1) * 4;  w = align_up(w, 16);
    int* bktcnt = (int*)w; w += (size_t)NB * 4;  w = align_up(w, 16);
    int* bktbase = (int*)w; w += (size_t)(NB + 1) * 4;  w = align_up(w, 64);
    int* bcnt = (int*)w; w += (size_t)NB * BPAD * 4;  w = align_up(w, 16);
    int* srcs = (int*)w; w += (size_t)E * 4;  w = align_up(w, 16);
    unsigned* ebuf = (unsigned*)w; w += (size_t)E * 4;
    (void)ws_size; (void)n_in; (void)out_size;

    const int OFF_IW0 = 0;                       // 4096 shorts (K=32 fragment)
    const int OFF_IW1 = 4096;
    const int OFF_IW2 = 4096 + 16384;
    const int OFF_IT = 4096 + 2 * 16384;

    WJobs jobs;
    int nj = 0;
    jobs.src[nj] = iW0; jobs.dstoff[nj] = OFF_IW0; jobs.ks[nj] = 5; nj++;
    jobs.src[nj] = iW1; jobs.dstoff[nj] = OFF_IW1; jobs.ks[nj] = 8; nj++;
    jobs.src[nj] = iW2; jobs.dstoff[nj] = OFF_IW2; jobs.ks[nj] = 8; nj++;
    for (int i = 0; i < n_iter && nj + 4 <= 16; i++) {
        int base = OFF_IT + i * 4 * 16384;
        jobs.src[nj] = nW0 + (size_t)i * 3 * HID * HID;               jobs.dstoff[nj] = base;             jobs.ks[nj] = 8; nj++;
        jobs.src[nj] = nW0 + (size_t)i * 3 * HID * HID + HID * HID;   jobs.dstoff[nj] = base + 16384;     jobs.ks[nj] = 8; nj++;
        jobs.src[nj] = nW1 + (size_t)i * HID * HID;                   jobs.dstoff[nj] = base + 2 * 16384; jobs.ks[nj] = 8; nj++;
        jobs.src[nj] = nW2 + (size_t)i * HID * HID;                   jobs.dstoff[nj] = base + 3 * 16384; jobs.ks[nj] = 8; nj++;
    }

    hipMemsetAsync(bktcnt, 0, (size_t)NB * 4, stream);  // must precede preph's hist part

    int cg = (E + CH - 1) / CH;
    preph_k<<<nj + cg, 256, 0, stream>>>(jobs, Wt, dst, bktcnt,
                                         gsums, (n_iter + 1) * HID, E, NB, nj);
    bscan_k<<<1, 1024, 0, stream>>>(bktcnt, bktbase, bcnt, row_ptr, NB, N, E);
    bin_k<<<cg, 1024, 0, stream>>>(src, dst, bcnt, ebuf, E, NB);

    int gbi = (N + 63) / 64;
    f2init_k<<<NB + gbi, 256, 0, stream>>>(ebuf, bktbase, row_ptr, deg, srcs,
                                           feat, Wt + OFF_IW0, Wt + OFF_IW1, Wt + OFF_IW2,
                                           ib0, ib1, ib2, h, hb, gsums, N, NB);

    int gb2 = (N + 63) / 64;
    int dpb = 4 * NDPW;
    int rb = (N + dpb - 1) / dpb;
    for (int i = 0; i < n_iter; i++) {
        const u16* Wit = Wt + OFF_IT + (size_t)i * 4 * 16384;
        const float* Wg = nW0 + (size_t)i * 3 * HID * HID + 2 * HID * HID;
        msg_k<<<rb + 1, 256, 0, stream>>>(hb, row_ptr, srcs, msgb, N,
                                          gsums + (size_t)i * HID, Wg, nb0 + (size_t)i * HID, grW);
        if (i + 1 < n_iter) {
            node_fused_k<false><<<gb2, 256, 0, stream>>>(msgb, hb, Wit, Wit + 16384, Wit + 2 * 16384,
                                                         Wit + 3 * 16384, grW, nb1 + (size_t)i * HID,
                                                         nb2 + (size_t)i * HID, deg, h, hb,
                                                         gsums + (size_t)(i + 1) * HID, N);
        } else {
            node_fused_k<true><<<gb2, 256, 0, stream>>>(msgb, hb, Wit, Wit + 16384, Wit + 2 * 16384,
                                                        Wit + 3 * 16384, grW, nb1 + (size_t)i * HID,
                                                        nb2 + (size_t)i * HID, deg, h, hb,
                                                        nullptr, N);
        }
    }
}